// Round 8
// baseline (2608.310 us; speedup 1.0000x reference)
//
#include <hip/hip_runtime.h>

#define NN 100000
#define EE 1000000
#define ELL 500000
#define NF (NN*64)

// new CSR layout needs (floats): dinv 100352 + cnt 100352 + rowptr 100352 + col 1e6 + 3*NF
#define WS_FLOATS_CSR (301056 + 1000000 + 3*NF)
// old fallback layout
#define WS_FLOATS_OLD (262144 + 3*NF)

// ---------------- Threefry-2x32 ----------------
__device__ __forceinline__ void threefry2x32(unsigned k0, unsigned k1, unsigned &x0, unsigned &x1){
  unsigned ks2 = k0 ^ k1 ^ 0x1BD11BDAu;
#define TF_R(R) { x0 += x1; x1 = (x1<<(R))|(x1>>(32-(R))); x1 ^= x0; }
  x0 += k0; x1 += k1;
  TF_R(13) TF_R(15) TF_R(26) TF_R(6)
  x0 += k1;  x1 += ks2 + 1u;
  TF_R(17) TF_R(29) TF_R(16) TF_R(24)
  x0 += ks2; x1 += k0 + 2u;
  TF_R(13) TF_R(15) TF_R(26) TF_R(6)
  x0 += k0;  x1 += k1 + 3u;
  TF_R(17) TF_R(29) TF_R(16) TF_R(24)
  x0 += k1;  x1 += ks2 + 4u;
  TF_R(13) TF_R(15) TF_R(26) TF_R(6)
  x0 += ks2; x1 += k0 + 5u;
#undef TF_R
}

// ---------------- diagnostics probe (fires only on failure) ----------------
__global__ void k_probe(const int* __restrict__ ei, unsigned hostbits, float* __restrict__ out){
  if (threadIdx.x != 0 || blockIdx.x != 0) return;
  unsigned bits = hostbits;
  { unsigned a=0u, b=0u; threefry2x32(0u, 0u, a, b);
    if (a != 0x6b200159u || b != 0x99ba4efeu) bits |= 1u; }
  if (bits) out[0] = 1.0e4f * (float)bits;
}

// ---------------- utility ----------------
__global__ void k_zero_int(int* __restrict__ p, int n){
  int i = blockIdx.x*256 + threadIdx.x;
  if (i < n) p[i] = 0;
}

__global__ void k_deg(const int* __restrict__ dst, int ne, int* __restrict__ cnt){
  int i = blockIdx.x*256 + threadIdx.x;
  if (i < ne) atomicAdd(&cnt[dst[i]], 1);
}

__global__ void k_dinv(const int* __restrict__ cnt, float* __restrict__ dinv, int n){
  int i = blockIdx.x*256 + threadIdx.x;
  if (i < n) dinv[i] = 1.0f / sqrtf((float)(cnt[i] + 1));
}

// ---------------- single-block chunked exclusive scan: cnt[n] -> rowptr[n+1] ----------------
__global__ __launch_bounds__(1024) void k_scan(const int* __restrict__ cnt, int* __restrict__ rowptr, int n){
  __shared__ int part[1024];
  int t = threadIdx.x;
  const int CH = (n + 1023) >> 10;
  int base = t * CH;
  int s = 0;
  for (int k = 0; k < CH; ++k){ int idx = base + k; if (idx < n) s += cnt[idx]; }
  part[t] = s;
  __syncthreads();
  // inclusive Hillis-Steele over per-thread totals
  for (int off = 1; off < 1024; off <<= 1){
    int tmp = 0;
    if (t >= off) tmp = part[t - off];
    __syncthreads();
    if (t >= off) part[t] += tmp;
    __syncthreads();
  }
  int run = part[t] - s;   // exclusive start of this thread's chunk
  for (int k = 0; k < CH; ++k){
    int idx = base + k;
    if (idx < n){ rowptr[idx] = run; run += cnt[idx]; }
  }
  if (t == 1023) rowptr[n] = part[1023];
}

// ---------------- CSR fill: col[slot] = src, slots per dst via atomic cursor ----------------
__global__ void k_fill(const int* __restrict__ src, const int* __restrict__ dst, int ne,
                       const int* __restrict__ rowptr, int* __restrict__ cursor, int* __restrict__ col){
  int e = blockIdx.x*256 + threadIdx.x;
  if (e >= ne) return;
  int d = dst[e];
  int p = atomicAdd(&cursor[d], 1);
  col[rowptr[d] + p] = src[e];
}

// ---------------- GEMM [nrows,64] @ [64,64], optional relu on input ----------------
template<bool RELU>
__global__ __launch_bounds__(256) void k_gemm64(const float* __restrict__ X, const float* __restrict__ W,
                                                int nrows, float* __restrict__ Y){
  __shared__ float Ws[64][64];
  int t = threadIdx.x;
  {
    const float4* W4 = (const float4*)W;
    float4* S4 = (float4*)&Ws[0][0];
    #pragma unroll
    for (int i = 0; i < 4; ++i) S4[t + 256*i] = W4[t + 256*i];
  }
  __syncthreads();
  int row = blockIdx.x*16 + (t>>4);
  if (row >= nrows) return;
  int c0 = (t & 15) * 4;
  const float4* Xr = (const float4*)(X + (size_t)row*64);
  float4 acc = make_float4(0.f,0.f,0.f,0.f);
  #pragma unroll
  for (int kk = 0; kk < 16; ++kk){
    float4 xv = Xr[kk];
    if (RELU){
      xv.x = fmaxf(xv.x, 0.f); xv.y = fmaxf(xv.y, 0.f);
      xv.z = fmaxf(xv.z, 0.f); xv.w = fmaxf(xv.w, 0.f);
    }
    int k = kk*4;
    float4 w0 = *(const float4*)&Ws[k+0][c0];
    float4 w1 = *(const float4*)&Ws[k+1][c0];
    float4 w2 = *(const float4*)&Ws[k+2][c0];
    float4 w3 = *(const float4*)&Ws[k+3][c0];
    acc.x = fmaf(xv.x, w0.x, acc.x); acc.y = fmaf(xv.x, w0.y, acc.y);
    acc.z = fmaf(xv.x, w0.z, acc.z); acc.w = fmaf(xv.x, w0.w, acc.w);
    acc.x = fmaf(xv.y, w1.x, acc.x); acc.y = fmaf(xv.y, w1.y, acc.y);
    acc.z = fmaf(xv.y, w1.z, acc.z); acc.w = fmaf(xv.y, w1.w, acc.w);
    acc.x = fmaf(xv.z, w2.x, acc.x); acc.y = fmaf(xv.z, w2.y, acc.y);
    acc.z = fmaf(xv.z, w2.z, acc.z); acc.w = fmaf(xv.z, w2.w, acc.w);
    acc.x = fmaf(xv.w, w3.x, acc.x); acc.y = fmaf(xv.w, w3.y, acc.y);
    acc.z = fmaf(xv.w, w3.z, acc.z); acc.w = fmaf(xv.w, w3.w, acc.w);
  }
  *(float4*)(Y + (size_t)row*64 + c0) = acc;
}

// ---------------- GEMM [nrows,64] @ [64,2] ----------------
template<bool RELU>
__global__ __launch_bounds__(256) void k_gemm2(const float* __restrict__ X, const float* __restrict__ W,
                                               int nrows, float* __restrict__ Y){
  __shared__ float Ws[128];
  int t = threadIdx.x;
  if (t < 128) Ws[t] = W[t];
  __syncthreads();
  int row = blockIdx.x*256 + t;
  if (row >= nrows) return;
  const float4* Xr = (const float4*)(X + (size_t)row*64);
  float a0 = 0.f, a1 = 0.f;
  #pragma unroll
  for (int kk = 0; kk < 16; ++kk){
    float4 xv = Xr[kk];
    if (RELU){ xv.x=fmaxf(xv.x,0.f); xv.y=fmaxf(xv.y,0.f); xv.z=fmaxf(xv.z,0.f); xv.w=fmaxf(xv.w,0.f); }
    int k = kk*4;
    a0 = fmaf(xv.x, Ws[2*k+0], a0); a1 = fmaf(xv.x, Ws[2*k+1], a1);
    a0 = fmaf(xv.y, Ws[2*k+2], a0); a1 = fmaf(xv.y, Ws[2*k+3], a1);
    a0 = fmaf(xv.z, Ws[2*k+4], a0); a1 = fmaf(xv.z, Ws[2*k+5], a1);
    a0 = fmaf(xv.w, Ws[2*k+6], a0); a1 = fmaf(xv.w, Ws[2*k+7], a1);
  }
  Y[(size_t)row*2]   = a0;
  Y[(size_t)row*2+1] = a1;
}

// ---------------- CSR gather conv: out[d] = dv*(sum_in h[s]*dinv[s] + h[d]*dv) + b ----------------
__global__ __launch_bounds__(256) void k_gather64(const int* __restrict__ rowptr, const int* __restrict__ col,
                                                  const float* __restrict__ h, const float* __restrict__ dinv,
                                                  const float* __restrict__ b, float* __restrict__ out){
  int lane = threadIdx.x & 63;
  int node = (blockIdx.x*256 + threadIdx.x) >> 6;
  if (node >= NN) return;
  int beg = rowptr[node], end = rowptr[node+1];
  float dv = dinv[node];
  float acc = h[(size_t)node*64 + lane] * dv;     // self-loop (one dv here, one at the end)
  for (int j = beg; j < end; ++j){
    int s = col[j];
    acc = fmaf(h[(size_t)s*64 + lane], dinv[s], acc);
  }
  out[(size_t)node*64 + lane] = acc * dv + b[lane];
}

// ---------------- CSR gather cross-layer agg: out[r] = (lf[r] + sum C[s]) / ds ----------------
__global__ __launch_bounds__(256) void k_agggather(const int* __restrict__ rowptr, const int* __restrict__ col,
                                                    const float* __restrict__ lf, const float* __restrict__ last,
                                                    const float* __restrict__ ds, int dsidx, float* __restrict__ out){
  int lane = threadIdx.x & 63;
  int node = (blockIdx.x*256 + threadIdx.x) >> 6;
  if (node >= NN) return;
  int beg = rowptr[node], end = rowptr[node+1];
  float acc = lf[(size_t)node*64 + lane];
  for (int j = beg; j < end; ++j){
    int s = col[j];
    acc += last[(size_t)s*64 + lane];
  }
  out[(size_t)node*64 + lane] = acc / ds[dsidx];
}

// ---------------- CSR gather final conv (D_out=2), thread per node ----------------
__global__ void k_gather2(const int* __restrict__ rowptr, const int* __restrict__ col,
                          const float* __restrict__ h2, const float* __restrict__ dinv,
                          const float* __restrict__ b, float* __restrict__ out){
  int d = blockIdx.x*256 + threadIdx.x;
  if (d >= NN) return;
  int beg = rowptr[d], end = rowptr[d+1];
  float dv = dinv[d];
  float a0 = h2[(size_t)d*2]   * dv;
  float a1 = h2[(size_t)d*2+1] * dv;
  for (int j = beg; j < end; ++j){
    int s = col[j];
    float w = dinv[s];
    a0 = fmaf(h2[(size_t)s*2],   w, a0);
    a1 = fmaf(h2[(size_t)s*2+1], w, a1);
  }
  out[(size_t)d*2]   = a0 * dv + b[0];
  out[(size_t)d*2+1] = a1 * dv + b[1];
}

// ---------------- dropout: verified XOR-fold partitionable threefry ----------------
__global__ void k_dropout(const float* __restrict__ last, float* __restrict__ xemb){
  unsigned i = blockIdx.x*256 + threadIdx.x;
  if (i >= NF) return;
  unsigned x0 = 0u, x1 = i;
  threefry2x32(0u, 42u, x0, x1);
  unsigned bits = x0 ^ x1;
  float u = __uint_as_float((bits >> 9) | 0x3f800000u) - 1.0f;
  xemb[i] = (u < 0.6f) ? last[i] / 0.6f : 0.0f;
}

// ======== fallback (atomic scatter) kernels — used only if ws too small for CSR ========
__global__ void k_convinit(const float* __restrict__ h, const float* __restrict__ dinv,
                           const float* __restrict__ b, float* __restrict__ out){
  int i = blockIdx.x*256 + threadIdx.x;
  if (i >= NF) return;
  int v = i >> 6, c = i & 63;
  float dv = dinv[v];
  out[i] = h[i]*dv*dv + b[c];
}
__global__ void k_scatter64(const int* __restrict__ src, const int* __restrict__ dst, int ne,
                            const float* __restrict__ h, const float* __restrict__ dinv,
                            float* __restrict__ out){
  int lane = threadIdx.x & 63;
  int wid  = (blockIdx.x*256 + threadIdx.x) >> 6;
  int nw   = (gridDim.x*256) >> 6;
  for (int e = wid; e < ne; e += nw){
    int s = src[e], d = dst[e];
    float coef = dinv[s]*dinv[d];
    atomicAdd(&out[d*64 + lane], h[s*64 + lane]*coef);
  }
}
__global__ void k_layeragg(const int* __restrict__ recv, const int* __restrict__ srcn, int ne,
                           const float* __restrict__ last, float* __restrict__ acc){
  int lane = threadIdx.x & 63;
  int wid  = (blockIdx.x*256 + threadIdx.x) >> 6;
  int nw   = (gridDim.x*256) >> 6;
  for (int e = wid; e < ne; e += nw){
    int r = recv[e], s = srcn[e];
    atomicAdd(&acc[r*64 + lane], last[s*64 + lane]);
  }
}
__global__ void k_scale(const float* __restrict__ in, const float* __restrict__ ds, int dsidx,
                        float* __restrict__ out){
  int i = blockIdx.x*256 + threadIdx.x;
  if (i < NF) out[i] = in[i] / ds[dsidx];
}
__global__ void k_convinit2(const float* __restrict__ h2, const float* __restrict__ dinv,
                            const float* __restrict__ b, float* __restrict__ out){
  int i = blockIdx.x*256 + threadIdx.x;
  if (i >= NN*2) return;
  int v = i >> 1, c = i & 1;
  float dv = dinv[v];
  out[i] = h2[i]*dv*dv + b[c];
}
__global__ void k_scatter2(const int* __restrict__ src, const int* __restrict__ dst, int ne,
                           const float* __restrict__ h2, const float* __restrict__ dinv,
                           float* __restrict__ out){
  int e = blockIdx.x*256 + threadIdx.x;
  if (e >= ne) return;
  int s = src[e], d = dst[e];
  float coef = dinv[s]*dinv[d];
  atomicAdd(&out[d*2 + 0], h2[s*2 + 0]*coef);
  atomicAdd(&out[d*2 + 1], h2[s*2 + 1]*coef);
}

extern "C" void kernel_launch(void* const* d_in, const int* in_sizes, int n_in,
                              void* d_out, int out_size, void* d_ws, size_t ws_size,
                              hipStream_t stream) {
  const float* x    = (const float*)d_in[0];
  const int*   ei   = (const int*)  d_in[1];
  const int*   lei  = (const int*)  d_in[2];
  const float* degs = (const float*)d_in[3];
  const float* lW1  = (const float*)d_in[4];
  const float* lb1  = (const float*)d_in[5];
  const float* lW2  = (const float*)d_in[6];
  const float* lb2  = (const float*)d_in[7];
  const float* pW1  = (const float*)d_in[8];
  const float* pb1  = (const float*)d_in[9];
  const float* pW2  = (const float*)d_in[10];
  const float* pb2  = (const float*)d_in[11];
  float* out = (float*)d_out;

  const int gN   = (NN + 255)/256;
  const int gE   = (EE + 255)/256;
  const int gEL  = (ELL + 255)/256;
  const int gNF  = (NF + 255)/256;
  const int gG   = (NN*64 + 255)/256;   // gather64 grid (wave per node)

  if (ws_size >= (size_t)WS_FLOATS_CSR * 4) {
    // ================= CSR gather path =================
    float* base   = (float*)d_ws;
    float* dinv   = base;                        // 100352 f
    int*   cnt    = (int*)(base + 100352);       // 100352 i (reused as fill cursor)
    int*   rowptr = (int*)(base + 200704);       // 100352 i (needs 100001)
    int*   col    = (int*)(base + 301056);       // 1,000,000 i
    float* A      = base + 1301056;
    float* B      = A + NF;
    float* C      = B + NF;

    // CSR build helper (as a lambda over launches)
    auto build_csr = [&](const int* srcp, const int* dstp, int ne, int gEdges, bool computeDinv){
      k_zero_int<<<gN, 256, 0, stream>>>(cnt, NN);
      k_deg<<<gEdges, 256, 0, stream>>>(dstp, ne, cnt);
      if (computeDinv) k_dinv<<<gN, 256, 0, stream>>>(cnt, dinv, NN);
      k_scan<<<1, 1024, 0, stream>>>(cnt, rowptr, NN);
      k_zero_int<<<gN, 256, 0, stream>>>(cnt, NN);
      k_fill<<<gEdges, 256, 0, stream>>>(srcp, dstp, ne, rowptr, cnt, col);
    };

    float* last = nullptr;
    // surface 0: gemm->A, gather->B, gemm->A, gather->C (last=C)
    // surface 1: gemm->A?, careful with aliasing; use explicit schedule below.
    {
      // ---- surface 0 ----
      const int* s0 = ei;              const int* d0 = ei + EE;
      build_csr(s0, d0, EE, gE, true);
      k_gemm64<false><<<6250, 256, 0, stream>>>(x, lW1, NN, A);
      k_gather64<<<gG, 256, 0, stream>>>(rowptr, col, A, dinv, lb1, B);
      k_gemm64<true><<<6250, 256, 0, stream>>>(B, lW2, NN, A);
      k_gather64<<<gG, 256, 0, stream>>>(rowptr, col, A, dinv, lb2, C);
      last = C;
      // ---- surface 1 ----
      const int* s1 = ei + 2*(size_t)EE;  const int* d1 = s1 + EE;
      build_csr(s1, d1, EE, gE, true);
      k_gemm64<false><<<6250, 256, 0, stream>>>(x + (size_t)NF, lW1 + 4096, NN, A);
      k_gather64<<<gG, 256, 0, stream>>>(rowptr, col, A, dinv, lb1 + 64, B);
      k_gemm64<true><<<6250, 256, 0, stream>>>(B, lW2 + 4096, NN, A);
      k_gather64<<<gG, 256, 0, stream>>>(rowptr, col, A, dinv, lb2 + 64, B);   // lf = B
      const int* r0 = lei;             const int* ls0 = lei + ELL;
      build_csr(ls0 /*src*/, r0 /*dst=recv*/, ELL, gEL, false);
      k_agggather<<<gG, 256, 0, stream>>>(rowptr, col, B /*lf*/, C /*last*/, degs, 0, A);
      last = A;
      // ---- surface 2 ----
      const int* s2 = ei + 4*(size_t)EE;  const int* d2 = s2 + EE;
      build_csr(s2, d2, EE, gE, true);
      k_gemm64<false><<<6250, 256, 0, stream>>>(x + 2*(size_t)NF, lW1 + 8192, NN, B);
      k_gather64<<<gG, 256, 0, stream>>>(rowptr, col, B, dinv, lb1 + 128, C);
      k_gemm64<true><<<6250, 256, 0, stream>>>(C, lW2 + 8192, NN, B);
      k_gather64<<<gG, 256, 0, stream>>>(rowptr, col, B, dinv, lb2 + 128, C); // lf = C
      const int* r1 = lei + 2*(size_t)ELL; const int* ls1 = r1 + ELL;
      build_csr(ls1, r1, ELL, gEL, false);
      k_agggather<<<gG, 256, 0, stream>>>(rowptr, col, C /*lf*/, A /*last*/, degs, 1, B);
      last = B;
      // ---- dropout: A = x_emb ----
      k_dropout<<<gNF, 256, 0, stream>>>(B, A);
      // ---- predictor (edge set 2; rebuild CSR, dinv unchanged) ----
      build_csr(s2, d2, EE, gE, false);
      k_gemm64<false><<<6250, 256, 0, stream>>>(A, pW1, NN, C);
      k_gather64<<<gG, 256, 0, stream>>>(rowptr, col, C, dinv, pb1, A);
      k_gemm2<true><<<gN, 256, 0, stream>>>(A, pW2, NN, B);
      k_gather2<<<gN, 256, 0, stream>>>(rowptr, col, B, dinv, pb2, out);
    }
    k_probe<<<1, 64, 0, stream>>>(ei, 0u, out);
    return;
  }

  // ================= fallback: verified atomic-scatter path =================
  float* base = (float*)d_ws;
  float* dinv = base;
  int*   cnt  = (int*)(base + 100352);
  float* A    = base + 262144;
  float* B    = A + NF;
  float* C    = B + NF;

  for (int i = 0; i < 3; ++i){
    const int* srcp = ei + (size_t)i*2*EE;
    const int* dstp = srcp + EE;
    k_zero_int<<<gN, 256, 0, stream>>>(cnt, NN);
    k_deg<<<gE, 256, 0, stream>>>(dstp, EE, cnt);
    k_dinv<<<gN, 256, 0, stream>>>(cnt, dinv, NN);
    k_gemm64<false><<<6250, 256, 0, stream>>>(x + (size_t)i*NF, lW1 + (size_t)i*64*64, NN, A);
    k_convinit<<<gNF, 256, 0, stream>>>(A, dinv, lb1 + (size_t)i*64, B);
    k_scatter64<<<8192, 256, 0, stream>>>(srcp, dstp, EE, A, dinv, B);
    k_gemm64<true><<<6250, 256, 0, stream>>>(B, lW2 + (size_t)i*64*64, NN, A);
    float* T = (i == 0) ? C : B;
    k_convinit<<<gNF, 256, 0, stream>>>(A, dinv, lb2 + (size_t)i*64, T);
    k_scatter64<<<8192, 256, 0, stream>>>(srcp, dstp, EE, A, dinv, T);
    if (i > 0){
      const int* recvp = lei + (size_t)(i-1)*2*ELL;
      const int* lsrcp = recvp + ELL;
      k_layeragg<<<4096, 256, 0, stream>>>(recvp, lsrcp, ELL, C, B);
      k_scale<<<gNF, 256, 0, stream>>>(B, degs, i-1, C);
    }
  }
  k_dropout<<<gNF, 256, 0, stream>>>(C, B);
  const int* srcp = ei + (size_t)2*2*EE;
  const int* dstp = srcp + EE;
  k_gemm64<false><<<6250, 256, 0, stream>>>(B, pW1, NN, A);
  k_convinit<<<gNF, 256, 0, stream>>>(A, dinv, pb1, C);
  k_scatter64<<<8192, 256, 0, stream>>>(srcp, dstp, EE, A, dinv, C);
  k_gemm2<true><<<gN, 256, 0, stream>>>(C, pW2, NN, B);
  k_convinit2<<<(NN*2 + 255)/256, 256, 0, stream>>>(B, dinv, pb2, out);
  k_scatter2<<<gE, 256, 0, stream>>>(srcp, dstp, EE, B, dinv, out);
  k_probe<<<1, 64, 0, stream>>>(ei, 0u, out);
}

// Round 9
// 1493.876 us; speedup vs baseline: 1.7460x; 1.7460x over previous
//
#include <hip/hip_runtime.h>

#define NN 100000
#define EE 1000000
#define ELL 500000
#define NF (NN*64)
#define NB_SCAN ((NN + 1023) / 1024)   // 98

// ws layouts (floats)
// common head: dinv 100352 | cnt 100352 | bsum 128 | rowptrA 100352 | colA 1e6
#define OFF_CNT    100352
#define OFF_BSUM   200704
#define OFF_RPA    200832
#define OFF_COLA   301184
#define OFF_RPB    1301184
#define OFF_COLB   1401536
#define WS_SINGLE  (1301184 + 3*NF)              // 82.0 MB
#define WS_DUAL    (2401536 + 3*NF)              // 86.4 MB
#define WS_OLD     (262144 + 3*NF)               // fallback

// ---------------- Threefry-2x32 ----------------
__device__ __forceinline__ void threefry2x32(unsigned k0, unsigned k1, unsigned &x0, unsigned &x1){
  unsigned ks2 = k0 ^ k1 ^ 0x1BD11BDAu;
#define TF_R(R) { x0 += x1; x1 = (x1<<(R))|(x1>>(32-(R))); x1 ^= x0; }
  x0 += k0; x1 += k1;
  TF_R(13) TF_R(15) TF_R(26) TF_R(6)
  x0 += k1;  x1 += ks2 + 1u;
  TF_R(17) TF_R(29) TF_R(16) TF_R(24)
  x0 += ks2; x1 += k0 + 2u;
  TF_R(13) TF_R(15) TF_R(26) TF_R(6)
  x0 += k0;  x1 += k1 + 3u;
  TF_R(17) TF_R(29) TF_R(16) TF_R(24)
  x0 += k1;  x1 += ks2 + 4u;
  TF_R(13) TF_R(15) TF_R(26) TF_R(6)
  x0 += ks2; x1 += k0 + 5u;
#undef TF_R
}

__global__ void k_probe(const int* __restrict__ ei, unsigned hostbits, float* __restrict__ out){
  if (threadIdx.x != 0 || blockIdx.x != 0) return;
  unsigned bits = hostbits;
  { unsigned a=0u, b=0u; threefry2x32(0u, 0u, a, b);
    if (a != 0x6b200159u || b != 0x99ba4efeu) bits |= 1u; }
  if (bits) out[0] = 1.0e4f * (float)bits;
}

// ---------------- utility ----------------
__global__ void k_zero_int(int* __restrict__ p, int n){
  int i = blockIdx.x*256 + threadIdx.x;
  if (i < n) p[i] = 0;
}

__global__ void k_deg(const int* __restrict__ dst, int ne, int* __restrict__ cnt){
  int i = blockIdx.x*256 + threadIdx.x;
  if (i < ne) atomicAdd(&cnt[dst[i]], 1);
}

__global__ void k_dinv(const int* __restrict__ cnt, float* __restrict__ dinv, int n){
  int i = blockIdx.x*256 + threadIdx.x;
  if (i < n) dinv[i] = 1.0f / sqrtf((float)(cnt[i] + 1));
}

// ---------------- multi-block exclusive scan: cnt[n] -> rowptr[n+1] ----------------
__global__ __launch_bounds__(1024) void k_scan1(const int* __restrict__ cnt, int* __restrict__ bsum, int n){
  __shared__ int lds[1024];
  int t = threadIdx.x, i = blockIdx.x*1024 + t;
  lds[t] = (i < n) ? cnt[i] : 0;
  __syncthreads();
  for (int off = 512; off > 0; off >>= 1){
    if (t < off) lds[t] += lds[t + off];
    __syncthreads();
  }
  if (t == 0) bsum[blockIdx.x] = lds[0];
}

__global__ __launch_bounds__(128) void k_scan2(int* __restrict__ bsum, int nb){
  __shared__ int lds[128];
  int t = threadIdx.x;
  int v = (t < nb) ? bsum[t] : 0;
  lds[t] = v;
  __syncthreads();
  for (int off = 1; off < 128; off <<= 1){
    int x = (t >= off) ? lds[t - off] : 0;
    __syncthreads();
    lds[t] += x;
    __syncthreads();
  }
  if (t < nb) bsum[t] = lds[t] - v;   // exclusive
}

__global__ __launch_bounds__(1024) void k_scan3(const int* __restrict__ cnt, const int* __restrict__ bsum,
                                                int* __restrict__ rowptr, int n){
  __shared__ int lds[1024];
  int t = threadIdx.x, i = blockIdx.x*1024 + t;
  int v = (i < n) ? cnt[i] : 0;
  lds[t] = v;
  __syncthreads();
  for (int off = 1; off < 1024; off <<= 1){
    int x = (t >= off) ? lds[t - off] : 0;
    __syncthreads();
    lds[t] += x;
    __syncthreads();
  }
  int excl = lds[t] - v + bsum[blockIdx.x];
  if (i < n)  rowptr[i] = excl;
  if (i == n-1) rowptr[n] = excl + v;
}

// ---------------- CSR fill ----------------
__global__ void k_fill(const int* __restrict__ src, const int* __restrict__ dst, int ne,
                       const int* __restrict__ rowptr, int* __restrict__ cursor, int* __restrict__ col){
  int e = blockIdx.x*256 + threadIdx.x;
  if (e >= ne) return;
  int d = dst[e];
  int p = atomicAdd(&cursor[d], 1);
  col[rowptr[d] + p] = src[e];
}

// ---------------- GEMM [nrows,64] @ [64,64], optional relu on input ----------------
template<bool RELU>
__global__ __launch_bounds__(256) void k_gemm64(const float* __restrict__ X, const float* __restrict__ W,
                                                int nrows, float* __restrict__ Y){
  __shared__ float Ws[64][64];
  int t = threadIdx.x;
  {
    const float4* W4 = (const float4*)W;
    float4* S4 = (float4*)&Ws[0][0];
    #pragma unroll
    for (int i = 0; i < 4; ++i) S4[t + 256*i] = W4[t + 256*i];
  }
  __syncthreads();
  int row = blockIdx.x*16 + (t>>4);
  if (row >= nrows) return;
  int c0 = (t & 15) * 4;
  const float4* Xr = (const float4*)(X + (size_t)row*64);
  float4 acc = make_float4(0.f,0.f,0.f,0.f);
  #pragma unroll
  for (int kk = 0; kk < 16; ++kk){
    float4 xv = Xr[kk];
    if (RELU){
      xv.x = fmaxf(xv.x, 0.f); xv.y = fmaxf(xv.y, 0.f);
      xv.z = fmaxf(xv.z, 0.f); xv.w = fmaxf(xv.w, 0.f);
    }
    int k = kk*4;
    float4 w0 = *(const float4*)&Ws[k+0][c0];
    float4 w1 = *(const float4*)&Ws[k+1][c0];
    float4 w2 = *(const float4*)&Ws[k+2][c0];
    float4 w3 = *(const float4*)&Ws[k+3][c0];
    acc.x = fmaf(xv.x, w0.x, acc.x); acc.y = fmaf(xv.x, w0.y, acc.y);
    acc.z = fmaf(xv.x, w0.z, acc.z); acc.w = fmaf(xv.x, w0.w, acc.w);
    acc.x = fmaf(xv.y, w1.x, acc.x); acc.y = fmaf(xv.y, w1.y, acc.y);
    acc.z = fmaf(xv.y, w1.z, acc.z); acc.w = fmaf(xv.y, w1.w, acc.w);
    acc.x = fmaf(xv.z, w2.x, acc.x); acc.y = fmaf(xv.z, w2.y, acc.y);
    acc.z = fmaf(xv.z, w2.z, acc.z); acc.w = fmaf(xv.z, w2.w, acc.w);
    acc.x = fmaf(xv.w, w3.x, acc.x); acc.y = fmaf(xv.w, w3.y, acc.y);
    acc.z = fmaf(xv.w, w3.z, acc.z); acc.w = fmaf(xv.w, w3.w, acc.w);
  }
  *(float4*)(Y + (size_t)row*64 + c0) = acc;
}

// ---------------- GEMM [nrows,64] @ [64,2] ----------------
template<bool RELU>
__global__ __launch_bounds__(256) void k_gemm2(const float* __restrict__ X, const float* __restrict__ W,
                                               int nrows, float* __restrict__ Y){
  __shared__ float Ws[128];
  int t = threadIdx.x;
  if (t < 128) Ws[t] = W[t];
  __syncthreads();
  int row = blockIdx.x*256 + t;
  if (row >= nrows) return;
  const float4* Xr = (const float4*)(X + (size_t)row*64);
  float a0 = 0.f, a1 = 0.f;
  #pragma unroll
  for (int kk = 0; kk < 16; ++kk){
    float4 xv = Xr[kk];
    if (RELU){ xv.x=fmaxf(xv.x,0.f); xv.y=fmaxf(xv.y,0.f); xv.z=fmaxf(xv.z,0.f); xv.w=fmaxf(xv.w,0.f); }
    int k = kk*4;
    a0 = fmaf(xv.x, Ws[2*k+0], a0); a1 = fmaf(xv.x, Ws[2*k+1], a1);
    a0 = fmaf(xv.y, Ws[2*k+2], a0); a1 = fmaf(xv.y, Ws[2*k+3], a1);
    a0 = fmaf(xv.z, Ws[2*k+4], a0); a1 = fmaf(xv.z, Ws[2*k+5], a1);
    a0 = fmaf(xv.w, Ws[2*k+6], a0); a1 = fmaf(xv.w, Ws[2*k+7], a1);
  }
  Y[(size_t)row*2]   = a0;
  Y[(size_t)row*2+1] = a1;
}

// ---------------- CSR gather conv ----------------
__global__ __launch_bounds__(256) void k_gather64(const int* __restrict__ rowptr, const int* __restrict__ col,
                                                  const float* __restrict__ h, const float* __restrict__ dinv,
                                                  const float* __restrict__ b, float* __restrict__ out){
  int lane = threadIdx.x & 63;
  int node = (blockIdx.x*256 + threadIdx.x) >> 6;
  if (node >= NN) return;
  int beg = rowptr[node], end = rowptr[node+1];
  float dv = dinv[node];
  float acc = h[(size_t)node*64 + lane] * dv;
  for (int j = beg; j < end; ++j){
    int s = col[j];
    acc = fmaf(h[(size_t)s*64 + lane], dinv[s], acc);
  }
  out[(size_t)node*64 + lane] = acc * dv + b[lane];
}

// ---------------- CSR gather cross-layer agg ----------------
__global__ __launch_bounds__(256) void k_agggather(const int* __restrict__ rowptr, const int* __restrict__ col,
                                                    const float* __restrict__ lf, const float* __restrict__ last,
                                                    const float* __restrict__ ds, int dsidx, float* __restrict__ out){
  int lane = threadIdx.x & 63;
  int node = (blockIdx.x*256 + threadIdx.x) >> 6;
  if (node >= NN) return;
  int beg = rowptr[node], end = rowptr[node+1];
  float acc = lf[(size_t)node*64 + lane];
  for (int j = beg; j < end; ++j){
    int s = col[j];
    acc += last[(size_t)s*64 + lane];
  }
  out[(size_t)node*64 + lane] = acc / ds[dsidx];
}

// ---------------- CSR gather final conv (D_out=2) ----------------
__global__ void k_gather2(const int* __restrict__ rowptr, const int* __restrict__ col,
                          const float* __restrict__ h2, const float* __restrict__ dinv,
                          const float* __restrict__ b, float* __restrict__ out){
  int d = blockIdx.x*256 + threadIdx.x;
  if (d >= NN) return;
  int beg = rowptr[d], end = rowptr[d+1];
  float dv = dinv[d];
  float a0 = h2[(size_t)d*2]   * dv;
  float a1 = h2[(size_t)d*2+1] * dv;
  for (int j = beg; j < end; ++j){
    int s = col[j];
    float w = dinv[s];
    a0 = fmaf(h2[(size_t)s*2],   w, a0);
    a1 = fmaf(h2[(size_t)s*2+1], w, a1);
  }
  out[(size_t)d*2]   = a0 * dv + b[0];
  out[(size_t)d*2+1] = a1 * dv + b[1];
}

// ---------------- dropout: verified XOR-fold partitionable threefry ----------------
__global__ void k_dropout(const float* __restrict__ last, float* __restrict__ xemb){
  unsigned i = blockIdx.x*256 + threadIdx.x;
  if (i >= NF) return;
  unsigned x0 = 0u, x1 = i;
  threefry2x32(0u, 42u, x0, x1);
  unsigned bits = x0 ^ x1;
  float u = __uint_as_float((bits >> 9) | 0x3f800000u) - 1.0f;
  xemb[i] = (u < 0.6f) ? last[i] / 0.6f : 0.0f;
}

// ======== fallback (atomic scatter) kernels ========
__global__ void k_convinit(const float* __restrict__ h, const float* __restrict__ dinv,
                           const float* __restrict__ b, float* __restrict__ out){
  int i = blockIdx.x*256 + threadIdx.x;
  if (i >= NF) return;
  int v = i >> 6, c = i & 63;
  float dv = dinv[v];
  out[i] = h[i]*dv*dv + b[c];
}
__global__ void k_scatter64(const int* __restrict__ src, const int* __restrict__ dst, int ne,
                            const float* __restrict__ h, const float* __restrict__ dinv,
                            float* __restrict__ out){
  int lane = threadIdx.x & 63;
  int wid  = (blockIdx.x*256 + threadIdx.x) >> 6;
  int nw   = (gridDim.x*256) >> 6;
  for (int e = wid; e < ne; e += nw){
    int s = src[e], d = dst[e];
    float coef = dinv[s]*dinv[d];
    atomicAdd(&out[d*64 + lane], h[s*64 + lane]*coef);
  }
}
__global__ void k_layeragg(const int* __restrict__ recv, const int* __restrict__ srcn, int ne,
                           const float* __restrict__ last, float* __restrict__ acc){
  int lane = threadIdx.x & 63;
  int wid  = (blockIdx.x*256 + threadIdx.x) >> 6;
  int nw   = (gridDim.x*256) >> 6;
  for (int e = wid; e < ne; e += nw){
    int r = recv[e], s = srcn[e];
    atomicAdd(&acc[r*64 + lane], last[s*64 + lane]);
  }
}
__global__ void k_scale(const float* __restrict__ in, const float* __restrict__ ds, int dsidx,
                        float* __restrict__ out){
  int i = blockIdx.x*256 + threadIdx.x;
  if (i < NF) out[i] = in[i] / ds[dsidx];
}
__global__ void k_convinit2(const float* __restrict__ h2, const float* __restrict__ dinv,
                            const float* __restrict__ b, float* __restrict__ out){
  int i = blockIdx.x*256 + threadIdx.x;
  if (i >= NN*2) return;
  int v = i >> 1, c = i & 1;
  float dv = dinv[v];
  out[i] = h2[i]*dv*dv + b[c];
}
__global__ void k_scatter2(const int* __restrict__ src, const int* __restrict__ dst, int ne,
                           const float* __restrict__ h2, const float* __restrict__ dinv,
                           float* __restrict__ out){
  int e = blockIdx.x*256 + threadIdx.x;
  if (e >= ne) return;
  int s = src[e], d = dst[e];
  float coef = dinv[s]*dinv[d];
  atomicAdd(&out[d*2 + 0], h2[s*2 + 0]*coef);
  atomicAdd(&out[d*2 + 1], h2[s*2 + 1]*coef);
}

extern "C" void kernel_launch(void* const* d_in, const int* in_sizes, int n_in,
                              void* d_out, int out_size, void* d_ws, size_t ws_size,
                              hipStream_t stream) {
  const float* x    = (const float*)d_in[0];
  const int*   ei   = (const int*)  d_in[1];
  const int*   lei  = (const int*)  d_in[2];
  const float* degs = (const float*)d_in[3];
  const float* lW1  = (const float*)d_in[4];
  const float* lb1  = (const float*)d_in[5];
  const float* lW2  = (const float*)d_in[6];
  const float* lb2  = (const float*)d_in[7];
  const float* pW1  = (const float*)d_in[8];
  const float* pb1  = (const float*)d_in[9];
  const float* pW2  = (const float*)d_in[10];
  const float* pb2  = (const float*)d_in[11];
  float* out = (float*)d_out;

  const int gN  = (NN + 255)/256;
  const int gE  = (EE + 255)/256;
  const int gEL = (ELL + 255)/256;
  const int gNF = (NF + 255)/256;
  const int gG  = (NN*64 + 255)/256;

  const bool dual   = ws_size >= (size_t)WS_DUAL * 4;
  const bool single = ws_size >= (size_t)WS_SINGLE * 4;

  if (single) {
    float* base   = (float*)d_ws;
    float* dinv   = base;
    int*   cnt    = (int*)(base + OFF_CNT);
    int*   bsum   = (int*)(base + OFF_BSUM);
    int*   rpA    = (int*)(base + OFF_RPA);
    int*   colA   = (int*)(base + OFF_COLA);
    int*   rpB    = dual ? (int*)(base + OFF_RPB)  : rpA;
    int*   colB   = dual ? (int*)(base + OFF_COLB) : colA;
    float* F0     = base + (dual ? OFF_COLB + 1000000 : OFF_RPB);
    float* F1     = F0 + NF;
    float* F2     = F1 + NF;

    auto build_csr = [&](const int* srcp, const int* dstp, int ne, int gEdges, bool computeDinv,
                         int* rowptr, int* col){
      k_zero_int<<<gN, 256, 0, stream>>>(cnt, NN);
      k_deg<<<gEdges, 256, 0, stream>>>(dstp, ne, cnt);
      if (computeDinv) k_dinv<<<gN, 256, 0, stream>>>(cnt, dinv, NN);
      k_scan1<<<NB_SCAN, 1024, 0, stream>>>(cnt, bsum, NN);
      k_scan2<<<1, 128, 0, stream>>>(bsum, NB_SCAN);
      k_scan3<<<NB_SCAN, 1024, 0, stream>>>(cnt, bsum, rowptr, NN);
      k_zero_int<<<gN, 256, 0, stream>>>(cnt, NN);
      k_fill<<<gEdges, 256, 0, stream>>>(srcp, dstp, ne, rowptr, cnt, col);
    };

    const int* s0 = ei;                  const int* d0 = s0 + EE;
    const int* s1 = ei + 2*(size_t)EE;   const int* d1 = s1 + EE;
    const int* s2 = ei + 4*(size_t)EE;   const int* d2 = s2 + EE;
    const int* r0 = lei;                 const int* ls0 = r0 + ELL;
    const int* r1 = lei + 2*(size_t)ELL; const int* ls1 = r1 + ELL;

    // ---- surface 0 ----
    build_csr(s0, d0, EE, gE, true, rpA, colA);
    k_gemm64<false><<<6250, 256, 0, stream>>>(x, lW1, NN, F0);
    k_gather64<<<gG, 256, 0, stream>>>(rpA, colA, F0, dinv, lb1, F1);
    k_gemm64<true><<<6250, 256, 0, stream>>>(F1, lW2, NN, F0);
    k_gather64<<<gG, 256, 0, stream>>>(rpA, colA, F0, dinv, lb2, F2);           // last = F2
    // ---- surface 1 ----
    build_csr(s1, d1, EE, gE, true, rpA, colA);
    k_gemm64<false><<<6250, 256, 0, stream>>>(x + (size_t)NF, lW1 + 4096, NN, F0);
    k_gather64<<<gG, 256, 0, stream>>>(rpA, colA, F0, dinv, lb1 + 64, F1);
    k_gemm64<true><<<6250, 256, 0, stream>>>(F1, lW2 + 4096, NN, F0);
    k_gather64<<<gG, 256, 0, stream>>>(rpA, colA, F0, dinv, lb2 + 64, F1);      // lf = F1
    build_csr(ls0, r0, ELL, gEL, false, rpB, colB);
    k_agggather<<<gG, 256, 0, stream>>>(rpB, colB, F1, F2, degs, 0, F0);        // last = F0
    // ---- surface 2 ----
    build_csr(s2, d2, EE, gE, true, rpA, colA);
    k_gemm64<false><<<6250, 256, 0, stream>>>(x + 2*(size_t)NF, lW1 + 8192, NN, F1);
    k_gather64<<<gG, 256, 0, stream>>>(rpA, colA, F1, dinv, lb1 + 128, F2);
    k_gemm64<true><<<6250, 256, 0, stream>>>(F2, lW2 + 8192, NN, F1);
    k_gather64<<<gG, 256, 0, stream>>>(rpA, colA, F1, dinv, lb2 + 128, F2);     // lf = F2
    build_csr(ls1, r1, ELL, gEL, false, rpB, colB);
    k_agggather<<<gG, 256, 0, stream>>>(rpB, colB, F2, F0, degs, 1, F1);        // last = F1
    // ---- dropout ----
    k_dropout<<<gNF, 256, 0, stream>>>(F1, F0);
    // ---- predictor (edge set 2) ----
    if (!dual) build_csr(s2, d2, EE, gE, false, rpA, colA);   // dual: slotA still holds s2
    k_gemm64<false><<<6250, 256, 0, stream>>>(F0, pW1, NN, F2);
    k_gather64<<<gG, 256, 0, stream>>>(rpA, colA, F2, dinv, pb1, F0);
    k_gemm2<true><<<gN, 256, 0, stream>>>(F0, pW2, NN, F1);
    k_gather2<<<gN, 256, 0, stream>>>(rpA, colA, F1, dinv, pb2, out);
    k_probe<<<1, 64, 0, stream>>>(ei, 0u, out);
    return;
  }

  // ================= fallback: verified atomic-scatter path =================
  float* base = (float*)d_ws;
  float* dinv = base;
  int*   cnt  = (int*)(base + 100352);
  float* A    = base + 262144;
  float* B    = A + NF;
  float* C    = B + NF;

  for (int i = 0; i < 3; ++i){
    const int* srcp = ei + (size_t)i*2*EE;
    const int* dstp = srcp + EE;
    k_zero_int<<<gN, 256, 0, stream>>>(cnt, NN);
    k_deg<<<gE, 256, 0, stream>>>(dstp, EE, cnt);
    k_dinv<<<gN, 256, 0, stream>>>(cnt, dinv, NN);
    k_gemm64<false><<<6250, 256, 0, stream>>>(x + (size_t)i*NF, lW1 + (size_t)i*64*64, NN, A);
    k_convinit<<<gNF, 256, 0, stream>>>(A, dinv, lb1 + (size_t)i*64, B);
    k_scatter64<<<8192, 256, 0, stream>>>(srcp, dstp, EE, A, dinv, B);
    k_gemm64<true><<<6250, 256, 0, stream>>>(B, lW2 + (size_t)i*64*64, NN, A);
    float* T = (i == 0) ? C : B;
    k_convinit<<<gNF, 256, 0, stream>>>(A, dinv, lb2 + (size_t)i*64, T);
    k_scatter64<<<8192, 256, 0, stream>>>(srcp, dstp, EE, A, dinv, T);
    if (i > 0){
      const int* recvp = lei + (size_t)(i-1)*2*ELL;
      const int* lsrcp = recvp + ELL;
      k_layeragg<<<4096, 256, 0, stream>>>(recvp, lsrcp, ELL, C, B);
      k_scale<<<gNF, 256, 0, stream>>>(B, degs, i-1, C);
    }
  }
  k_dropout<<<gNF, 256, 0, stream>>>(C, B);
  const int* srcp = ei + (size_t)2*2*EE;
  const int* dstp = srcp + EE;
  k_gemm64<false><<<6250, 256, 0, stream>>>(B, pW1, NN, A);
  k_convinit<<<gNF, 256, 0, stream>>>(A, dinv, pb1, C);
  k_scatter64<<<8192, 256, 0, stream>>>(srcp, dstp, EE, A, dinv, C);
  k_gemm2<true><<<gN, 256, 0, stream>>>(C, pW2, NN, B);
  k_convinit2<<<(NN*2 + 255)/256, 256, 0, stream>>>(B, dinv, pb2, out);
  k_scatter2<<<gE, 256, 0, stream>>>(srcp, dstp, EE, B, dinv, out);
  k_probe<<<1, 64, 0, stream>>>(ei, 0u, out);
}

// Round 10
// 1053.094 us; speedup vs baseline: 2.4768x; 1.4186x over previous
//
#include <hip/hip_runtime.h>

#define NN 100000
#define EE 1000000
#define ELL 500000
#define NF (NN*64)
#define NB_SCAN ((NN + 1023) / 1024)   // 98

// ws layouts (floats)
#define OFF_CNT    100352
#define OFF_BSUM   200704
#define OFF_RPA    200832
#define OFF_COLA   301184
#define OFF_RPB    1301184
#define OFF_COLB   1401536
#define WS_SINGLE  (1301184 + 3*NF)              // 82.0 MB
#define WS_DUAL    (2401536 + 3*NF)              // 86.4 MB

// ---------------- Threefry-2x32 ----------------
__device__ __forceinline__ void threefry2x32(unsigned k0, unsigned k1, unsigned &x0, unsigned &x1){
  unsigned ks2 = k0 ^ k1 ^ 0x1BD11BDAu;
#define TF_R(R) { x0 += x1; x1 = (x1<<(R))|(x1>>(32-(R))); x1 ^= x0; }
  x0 += k0; x1 += k1;
  TF_R(13) TF_R(15) TF_R(26) TF_R(6)
  x0 += k1;  x1 += ks2 + 1u;
  TF_R(17) TF_R(29) TF_R(16) TF_R(24)
  x0 += ks2; x1 += k0 + 2u;
  TF_R(13) TF_R(15) TF_R(26) TF_R(6)
  x0 += k0;  x1 += k1 + 3u;
  TF_R(17) TF_R(29) TF_R(16) TF_R(24)
  x0 += k1;  x1 += ks2 + 4u;
  TF_R(13) TF_R(15) TF_R(26) TF_R(6)
  x0 += ks2; x1 += k0 + 5u;
#undef TF_R
}

__device__ __forceinline__ float dropout_val(float v, unsigned i){
  unsigned x0 = 0u, x1 = i;
  threefry2x32(0u, 42u, x0, x1);
  unsigned bits = x0 ^ x1;
  float u = __uint_as_float((bits >> 9) | 0x3f800000u) - 1.0f;
  return (u < 0.6f) ? v * (1.0f/0.6f) : 0.0f;
}

__global__ void k_probe(const int* __restrict__ ei, unsigned hostbits, float* __restrict__ out){
  if (threadIdx.x != 0 || blockIdx.x != 0) return;
  unsigned bits = hostbits;
  { unsigned a=0u, b=0u; threefry2x32(0u, 0u, a, b);
    if (a != 0x6b200159u || b != 0x99ba4efeu) bits |= 1u; }
  if (bits) out[0] = 1.0e4f * (float)bits;
}

// ---------------- utility ----------------
__global__ void k_zero_int(int* __restrict__ p, int n){
  int i = blockIdx.x*256 + threadIdx.x;
  if (i < n) p[i] = 0;
}

__global__ void k_deg(const int* __restrict__ dst, int ne, int* __restrict__ cnt){
  int i = blockIdx.x*256 + threadIdx.x;
  if (i < ne) atomicAdd(&cnt[dst[i]], 1);
}

__global__ void k_dinv(const int* __restrict__ cnt, float* __restrict__ dinv, int n){
  int i = blockIdx.x*256 + threadIdx.x;
  if (i < n) dinv[i] = 1.0f / sqrtf((float)(cnt[i] + 1));
}

// ---------------- multi-block exclusive scan ----------------
__global__ __launch_bounds__(1024) void k_scan1(const int* __restrict__ cnt, int* __restrict__ bsum, int n){
  __shared__ int lds[1024];
  int t = threadIdx.x, i = blockIdx.x*1024 + t;
  lds[t] = (i < n) ? cnt[i] : 0;
  __syncthreads();
  for (int off = 512; off > 0; off >>= 1){
    if (t < off) lds[t] += lds[t + off];
    __syncthreads();
  }
  if (t == 0) bsum[blockIdx.x] = lds[0];
}

__global__ __launch_bounds__(128) void k_scan2(int* __restrict__ bsum, int nb){
  __shared__ int lds[128];
  int t = threadIdx.x;
  int v = (t < nb) ? bsum[t] : 0;
  lds[t] = v;
  __syncthreads();
  for (int off = 1; off < 128; off <<= 1){
    int x = (t >= off) ? lds[t - off] : 0;
    __syncthreads();
    lds[t] += x;
    __syncthreads();
  }
  if (t < nb) bsum[t] = lds[t] - v;
}

__global__ __launch_bounds__(1024) void k_scan3(const int* __restrict__ cnt, const int* __restrict__ bsum,
                                                int* __restrict__ rowptr, int n){
  __shared__ int lds[1024];
  int t = threadIdx.x, i = blockIdx.x*1024 + t;
  int v = (i < n) ? cnt[i] : 0;
  lds[t] = v;
  __syncthreads();
  for (int off = 1; off < 1024; off <<= 1){
    int x = (t >= off) ? lds[t - off] : 0;
    __syncthreads();
    lds[t] += x;
    __syncthreads();
  }
  int excl = lds[t] - v + bsum[blockIdx.x];
  if (i < n)  rowptr[i] = excl;
  if (i == n-1) rowptr[n] = excl + v;
}

// ---------------- CSR fill ----------------
__global__ void k_fill(const int* __restrict__ src, const int* __restrict__ dst, int ne,
                       const int* __restrict__ rowptr, int* __restrict__ cursor, int* __restrict__ col){
  int e = blockIdx.x*256 + threadIdx.x;
  if (e >= ne) return;
  int d = dst[e];
  int p = atomicAdd(&cursor[d], 1);
  col[rowptr[d] + p] = src[e];
}

// ---------------- GEMM [nrows,64] @ [64,64]; RELU on input; SCALE: Y[row] *= dinv[row] ----------------
template<bool RELU, bool SCALE>
__global__ __launch_bounds__(256) void k_gemm64(const float* __restrict__ X, const float* __restrict__ W,
                                                const float* __restrict__ dinv,
                                                int nrows, float* __restrict__ Y){
  __shared__ float Ws[64][64];
  int t = threadIdx.x;
  {
    const float4* W4 = (const float4*)W;
    float4* S4 = (float4*)&Ws[0][0];
    #pragma unroll
    for (int i = 0; i < 4; ++i) S4[t + 256*i] = W4[t + 256*i];
  }
  __syncthreads();
  int row = blockIdx.x*16 + (t>>4);
  if (row >= nrows) return;
  int c0 = (t & 15) * 4;
  const float4* Xr = (const float4*)(X + (size_t)row*64);
  float4 acc = make_float4(0.f,0.f,0.f,0.f);
  #pragma unroll
  for (int kk = 0; kk < 16; ++kk){
    float4 xv = Xr[kk];
    if (RELU){
      xv.x = fmaxf(xv.x, 0.f); xv.y = fmaxf(xv.y, 0.f);
      xv.z = fmaxf(xv.z, 0.f); xv.w = fmaxf(xv.w, 0.f);
    }
    int k = kk*4;
    float4 w0 = *(const float4*)&Ws[k+0][c0];
    float4 w1 = *(const float4*)&Ws[k+1][c0];
    float4 w2 = *(const float4*)&Ws[k+2][c0];
    float4 w3 = *(const float4*)&Ws[k+3][c0];
    acc.x = fmaf(xv.x, w0.x, acc.x); acc.y = fmaf(xv.x, w0.y, acc.y);
    acc.z = fmaf(xv.x, w0.z, acc.z); acc.w = fmaf(xv.x, w0.w, acc.w);
    acc.x = fmaf(xv.y, w1.x, acc.x); acc.y = fmaf(xv.y, w1.y, acc.y);
    acc.z = fmaf(xv.y, w1.z, acc.z); acc.w = fmaf(xv.y, w1.w, acc.w);
    acc.x = fmaf(xv.z, w2.x, acc.x); acc.y = fmaf(xv.z, w2.y, acc.y);
    acc.z = fmaf(xv.z, w2.z, acc.z); acc.w = fmaf(xv.z, w2.w, acc.w);
    acc.x = fmaf(xv.w, w3.x, acc.x); acc.y = fmaf(xv.w, w3.y, acc.y);
    acc.z = fmaf(xv.w, w3.z, acc.z); acc.w = fmaf(xv.w, w3.w, acc.w);
  }
  if (SCALE){
    float dv = dinv[row];
    acc.x *= dv; acc.y *= dv; acc.z *= dv; acc.w *= dv;
  }
  *(float4*)(Y + (size_t)row*64 + c0) = acc;
}

// ---------------- GEMM [nrows,64] @ [64,2] ----------------
template<bool RELU, bool SCALE>
__global__ __launch_bounds__(256) void k_gemm2(const float* __restrict__ X, const float* __restrict__ W,
                                               const float* __restrict__ dinv,
                                               int nrows, float* __restrict__ Y){
  __shared__ float Ws[128];
  int t = threadIdx.x;
  if (t < 128) Ws[t] = W[t];
  __syncthreads();
  int row = blockIdx.x*256 + t;
  if (row >= nrows) return;
  const float4* Xr = (const float4*)(X + (size_t)row*64);
  float a0 = 0.f, a1 = 0.f;
  #pragma unroll
  for (int kk = 0; kk < 16; ++kk){
    float4 xv = Xr[kk];
    if (RELU){ xv.x=fmaxf(xv.x,0.f); xv.y=fmaxf(xv.y,0.f); xv.z=fmaxf(xv.z,0.f); xv.w=fmaxf(xv.w,0.f); }
    int k = kk*4;
    a0 = fmaf(xv.x, Ws[2*k+0], a0); a1 = fmaf(xv.x, Ws[2*k+1], a1);
    a0 = fmaf(xv.y, Ws[2*k+2], a0); a1 = fmaf(xv.y, Ws[2*k+3], a1);
    a0 = fmaf(xv.z, Ws[2*k+4], a0); a1 = fmaf(xv.z, Ws[2*k+5], a1);
    a0 = fmaf(xv.w, Ws[2*k+6], a0); a1 = fmaf(xv.w, Ws[2*k+7], a1);
  }
  if (SCALE){ float dv = dinv[row]; a0 *= dv; a1 *= dv; }
  Y[(size_t)row*2]   = a0;
  Y[(size_t)row*2+1] = a1;
}

// ---------------- CSR gather conv on pre-scaled h' (= h*dinv): out = dv*Σ + b ----------------
__global__ __launch_bounds__(256) void k_gather64(const int* __restrict__ rowptr, const int* __restrict__ col,
                                                  const float* __restrict__ h, const float* __restrict__ dinv,
                                                  const float* __restrict__ b, float* __restrict__ out){
  int lane = threadIdx.x & 63;
  int node = (blockIdx.x*256 + threadIdx.x) >> 6;
  if (node >= NN) return;
  int beg = rowptr[node], end = rowptr[node+1];
  float acc = h[(size_t)node*64 + lane];          // self-loop: h' already scaled
  int j = beg;
  for (; j + 4 <= end; j += 4){
    int s0 = col[j], s1 = col[j+1], s2 = col[j+2], s3 = col[j+3];
    float h0 = h[(size_t)s0*64 + lane];
    float h1 = h[(size_t)s1*64 + lane];
    float h2 = h[(size_t)s2*64 + lane];
    float h3 = h[(size_t)s3*64 + lane];
    acc += h0; acc += h1; acc += h2; acc += h3;
  }
  for (; j < end; ++j) acc += h[(size_t)col[j]*64 + lane];
  out[(size_t)node*64 + lane] = fmaf(acc, dinv[node], b[lane]);
}

// ---------------- CSR gather cross-layer agg (+ optional fused dropout) ----------------
template<bool DROP>
__global__ __launch_bounds__(256) void k_agggather(const int* __restrict__ rowptr, const int* __restrict__ col,
                                                    const float* __restrict__ lf, const float* __restrict__ last,
                                                    const float* __restrict__ ds, int dsidx, float* __restrict__ out){
  int lane = threadIdx.x & 63;
  int node = (blockIdx.x*256 + threadIdx.x) >> 6;
  if (node >= NN) return;
  int beg = rowptr[node], end = rowptr[node+1];
  float acc = lf[(size_t)node*64 + lane];
  int j = beg;
  for (; j + 4 <= end; j += 4){
    int s0 = col[j], s1 = col[j+1], s2 = col[j+2], s3 = col[j+3];
    float h0 = last[(size_t)s0*64 + lane];
    float h1 = last[(size_t)s1*64 + lane];
    float h2 = last[(size_t)s2*64 + lane];
    float h3 = last[(size_t)s3*64 + lane];
    acc += h0; acc += h1; acc += h2; acc += h3;
  }
  for (; j < end; ++j) acc += last[(size_t)col[j]*64 + lane];
  float val = acc / ds[dsidx];
  unsigned i = (unsigned)node*64u + (unsigned)lane;
  if (DROP) val = dropout_val(val, i);
  out[i] = val;
}

// ---------------- CSR gather final conv (D_out=2) on pre-scaled h2' ----------------
__global__ void k_gather2(const int* __restrict__ rowptr, const int* __restrict__ col,
                          const float* __restrict__ h2, const float* __restrict__ dinv,
                          const float* __restrict__ b, float* __restrict__ out){
  int d = blockIdx.x*256 + threadIdx.x;
  if (d >= NN) return;
  int beg = rowptr[d], end = rowptr[d+1];
  float a0 = h2[(size_t)d*2];
  float a1 = h2[(size_t)d*2+1];
  for (int j = beg; j < end; ++j){
    int s = col[j];
    a0 += h2[(size_t)s*2];
    a1 += h2[(size_t)s*2+1];
  }
  float dv = dinv[d];
  out[(size_t)d*2]   = fmaf(a0, dv, b[0]);
  out[(size_t)d*2+1] = fmaf(a1, dv, b[1]);
}

// ---------------- standalone dropout (fallback path only) ----------------
__global__ void k_dropout(const float* __restrict__ last, float* __restrict__ xemb){
  unsigned i = blockIdx.x*256 + threadIdx.x;
  if (i >= NF) return;
  xemb[i] = dropout_val(last[i], i);
}

// ======== fallback (atomic scatter) kernels ========
__global__ void k_convinit(const float* __restrict__ h, const float* __restrict__ dinv,
                           const float* __restrict__ b, float* __restrict__ out){
  int i = blockIdx.x*256 + threadIdx.x;
  if (i >= NF) return;
  int v = i >> 6, c = i & 63;
  float dv = dinv[v];
  out[i] = h[i]*dv*dv + b[c];
}
__global__ void k_scatter64(const int* __restrict__ src, const int* __restrict__ dst, int ne,
                            const float* __restrict__ h, const float* __restrict__ dinv,
                            float* __restrict__ out){
  int lane = threadIdx.x & 63;
  int wid  = (blockIdx.x*256 + threadIdx.x) >> 6;
  int nw   = (gridDim.x*256) >> 6;
  for (int e = wid; e < ne; e += nw){
    int s = src[e], d = dst[e];
    float coef = dinv[s]*dinv[d];
    atomicAdd(&out[d*64 + lane], h[s*64 + lane]*coef);
  }
}
__global__ void k_layeragg(const int* __restrict__ recv, const int* __restrict__ srcn, int ne,
                           const float* __restrict__ last, float* __restrict__ acc){
  int lane = threadIdx.x & 63;
  int wid  = (blockIdx.x*256 + threadIdx.x) >> 6;
  int nw   = (gridDim.x*256) >> 6;
  for (int e = wid; e < ne; e += nw){
    int r = recv[e], s = srcn[e];
    atomicAdd(&acc[r*64 + lane], last[s*64 + lane]);
  }
}
__global__ void k_scale(const float* __restrict__ in, const float* __restrict__ ds, int dsidx,
                        float* __restrict__ out){
  int i = blockIdx.x*256 + threadIdx.x;
  if (i < NF) out[i] = in[i] / ds[dsidx];
}
__global__ void k_convinit2(const float* __restrict__ h2, const float* __restrict__ dinv,
                            const float* __restrict__ b, float* __restrict__ out){
  int i = blockIdx.x*256 + threadIdx.x;
  if (i >= NN*2) return;
  int v = i >> 1, c = i & 1;
  float dv = dinv[v];
  out[i] = h2[i]*dv*dv + b[c];
}
__global__ void k_scatter2(const int* __restrict__ src, const int* __restrict__ dst, int ne,
                           const float* __restrict__ h2, const float* __restrict__ dinv,
                           float* __restrict__ out){
  int e = blockIdx.x*256 + threadIdx.x;
  if (e >= ne) return;
  int s = src[e], d = dst[e];
  float coef = dinv[s]*dinv[d];
  atomicAdd(&out[d*2 + 0], h2[s*2 + 0]*coef);
  atomicAdd(&out[d*2 + 1], h2[s*2 + 1]*coef);
}

extern "C" void kernel_launch(void* const* d_in, const int* in_sizes, int n_in,
                              void* d_out, int out_size, void* d_ws, size_t ws_size,
                              hipStream_t stream) {
  const float* x    = (const float*)d_in[0];
  const int*   ei   = (const int*)  d_in[1];
  const int*   lei  = (const int*)  d_in[2];
  const float* degs = (const float*)d_in[3];
  const float* lW1  = (const float*)d_in[4];
  const float* lb1  = (const float*)d_in[5];
  const float* lW2  = (const float*)d_in[6];
  const float* lb2  = (const float*)d_in[7];
  const float* pW1  = (const float*)d_in[8];
  const float* pb1  = (const float*)d_in[9];
  const float* pW2  = (const float*)d_in[10];
  const float* pb2  = (const float*)d_in[11];
  float* out = (float*)d_out;

  const int gN  = (NN + 255)/256;
  const int gE  = (EE + 255)/256;
  const int gEL = (ELL + 255)/256;
  const int gNF = (NF + 255)/256;
  const int gG  = (NN*64 + 255)/256;

  const bool dual   = ws_size >= (size_t)WS_DUAL * 4;
  const bool single = ws_size >= (size_t)WS_SINGLE * 4;

  if (single) {
    float* base   = (float*)d_ws;
    float* dinv   = base;
    int*   cnt    = (int*)(base + OFF_CNT);
    int*   bsum   = (int*)(base + OFF_BSUM);
    int*   rpA    = (int*)(base + OFF_RPA);
    int*   colA   = (int*)(base + OFF_COLA);
    int*   rpB    = dual ? (int*)(base + OFF_RPB)  : rpA;
    int*   colB   = dual ? (int*)(base + OFF_COLB) : colA;
    float* F0     = base + (dual ? OFF_COLB + 1000000 : OFF_RPB);
    float* F1     = F0 + NF;
    float* F2     = F1 + NF;

    auto build_csr = [&](const int* srcp, const int* dstp, int ne, int gEdges, bool computeDinv,
                         int* rowptr, int* col){
      k_zero_int<<<gN, 256, 0, stream>>>(cnt, NN);
      k_deg<<<gEdges, 256, 0, stream>>>(dstp, ne, cnt);
      if (computeDinv) k_dinv<<<gN, 256, 0, stream>>>(cnt, dinv, NN);
      k_scan1<<<NB_SCAN, 1024, 0, stream>>>(cnt, bsum, NN);
      k_scan2<<<1, 128, 0, stream>>>(bsum, NB_SCAN);
      k_scan3<<<NB_SCAN, 1024, 0, stream>>>(cnt, bsum, rowptr, NN);
      k_zero_int<<<gN, 256, 0, stream>>>(cnt, NN);
      k_fill<<<gEdges, 256, 0, stream>>>(srcp, dstp, ne, rowptr, cnt, col);
    };

    const int* s0 = ei;                  const int* d0 = s0 + EE;
    const int* s1 = ei + 2*(size_t)EE;   const int* d1 = s1 + EE;
    const int* s2 = ei + 4*(size_t)EE;   const int* d2 = s2 + EE;
    const int* r0 = lei;                 const int* ls0 = r0 + ELL;
    const int* r1 = lei + 2*(size_t)ELL; const int* ls1 = r1 + ELL;

    // ---- surface 0 ----
    build_csr(s0, d0, EE, gE, true, rpA, colA);
    k_gemm64<false,true><<<6250, 256, 0, stream>>>(x, lW1, dinv, NN, F0);
    k_gather64<<<gG, 256, 0, stream>>>(rpA, colA, F0, dinv, lb1, F1);
    k_gemm64<true,true><<<6250, 256, 0, stream>>>(F1, lW2, dinv, NN, F0);
    k_gather64<<<gG, 256, 0, stream>>>(rpA, colA, F0, dinv, lb2, F2);            // last = F2
    // ---- surface 1 ----
    build_csr(s1, d1, EE, gE, true, rpA, colA);
    k_gemm64<false,true><<<6250, 256, 0, stream>>>(x + (size_t)NF, lW1 + 4096, dinv, NN, F0);
    k_gather64<<<gG, 256, 0, stream>>>(rpA, colA, F0, dinv, lb1 + 64, F1);
    k_gemm64<true,true><<<6250, 256, 0, stream>>>(F1, lW2 + 4096, dinv, NN, F0);
    k_gather64<<<gG, 256, 0, stream>>>(rpA, colA, F0, dinv, lb2 + 64, F1);       // lf = F1
    build_csr(ls0, r0, ELL, gEL, false, rpB, colB);
    k_agggather<false><<<gG, 256, 0, stream>>>(rpB, colB, F1, F2, degs, 0, F0);  // last = F0
    // ---- surface 2 ----
    build_csr(s2, d2, EE, gE, true, rpA, colA);
    k_gemm64<false,true><<<6250, 256, 0, stream>>>(x + 2*(size_t)NF, lW1 + 8192, dinv, NN, F1);
    k_gather64<<<gG, 256, 0, stream>>>(rpA, colA, F1, dinv, lb1 + 128, F2);
    k_gemm64<true,true><<<6250, 256, 0, stream>>>(F2, lW2 + 8192, dinv, NN, F1);
    k_gather64<<<gG, 256, 0, stream>>>(rpA, colA, F1, dinv, lb2 + 128, F2);      // lf = F2
    build_csr(ls1, r1, ELL, gEL, false, rpB, colB);
    k_agggather<true><<<gG, 256, 0, stream>>>(rpB, colB, F2, F0, degs, 1, F1);   // F1 = x_emb (dropout fused)
    // ---- predictor (edge set 2) ----
    if (!dual) build_csr(s2, d2, EE, gE, false, rpA, colA);
    k_gemm64<false,true><<<6250, 256, 0, stream>>>(F1, pW1, dinv, NN, F0);
    k_gather64<<<gG, 256, 0, stream>>>(rpA, colA, F0, dinv, pb1, F2);
    k_gemm2<true,true><<<gN, 256, 0, stream>>>(F2, pW2, dinv, NN, F1);
    k_gather2<<<gN, 256, 0, stream>>>(rpA, colA, F1, dinv, pb2, out);
    k_probe<<<1, 64, 0, stream>>>(ei, 0u, out);
    return;
  }

  // ================= fallback: verified atomic-scatter path =================
  float* base = (float*)d_ws;
  float* dinv = base;
  int*   cnt  = (int*)(base + 100352);
  float* A    = base + 262144;
  float* B    = A + NF;
  float* C    = B + NF;

  for (int i = 0; i < 3; ++i){
    const int* srcp = ei + (size_t)i*2*EE;
    const int* dstp = srcp + EE;
    k_zero_int<<<gN, 256, 0, stream>>>(cnt, NN);
    k_deg<<<gE, 256, 0, stream>>>(dstp, EE, cnt);
    k_dinv<<<gN, 256, 0, stream>>>(cnt, dinv, NN);
    k_gemm64<false,false><<<6250, 256, 0, stream>>>(x + (size_t)i*NF, lW1 + (size_t)i*64*64, dinv, NN, A);
    k_convinit<<<gNF, 256, 0, stream>>>(A, dinv, lb1 + (size_t)i*64, B);
    k_scatter64<<<8192, 256, 0, stream>>>(srcp, dstp, EE, A, dinv, B);
    k_gemm64<true,false><<<6250, 256, 0, stream>>>(B, lW2 + (size_t)i*64*64, dinv, NN, A);
    float* T = (i == 0) ? C : B;
    k_convinit<<<gNF, 256, 0, stream>>>(A, dinv, lb2 + (size_t)i*64, T);
    k_scatter64<<<8192, 256, 0, stream>>>(srcp, dstp, EE, A, dinv, T);
    if (i > 0){
      const int* recvp = lei + (size_t)(i-1)*2*ELL;
      const int* lsrcp = recvp + ELL;
      k_layeragg<<<4096, 256, 0, stream>>>(recvp, lsrcp, ELL, C, B);
      k_scale<<<gNF, 256, 0, stream>>>(B, degs, i-1, C);
    }
  }
  k_dropout<<<gNF, 256, 0, stream>>>(C, B);
  const int* srcp = ei + (size_t)2*2*EE;
  const int* dstp = srcp + EE;
  k_gemm64<false,false><<<6250, 256, 0, stream>>>(B, pW1, dinv, NN, A);
  k_convinit<<<gNF, 256, 0, stream>>>(A, dinv, pb1, C);
  k_scatter64<<<8192, 256, 0, stream>>>(srcp, dstp, EE, A, dinv, C);
  k_gemm2<true,false><<<gN, 256, 0, stream>>>(C, pW2, dinv, NN, B);
  k_convinit2<<<(NN*2 + 255)/256, 256, 0, stream>>>(B, dinv, pb2, out);
  k_scatter2<<<gE, 256, 0, stream>>>(srcp, dstp, EE, B, dinv, out);
  k_probe<<<1, 64, 0, stream>>>(ei, 0u, out);
}

// Round 11
// 914.520 us; speedup vs baseline: 2.8521x; 1.1515x over previous
//
#include <hip/hip_runtime.h>

#define NN 100000
#define EE 1000000
#define ELL 500000
#define NF (NN*64)
#define NB_SCAN ((NN + 1023) / 1024)   // 98

// ws layouts (floats)
#define OFF_CNT    100352
#define OFF_BSUM   200704
#define OFF_RPA    200832
#define OFF_COLA   301184
#define OFF_RPB    1301184
#define OFF_COLB   1401536
#define WS_SINGLE  (1301184 + 3*NF)              // 82.0 MB
#define WS_DUAL    (2401536 + 3*NF)              // 86.4 MB

// ---------------- Threefry-2x32 ----------------
__device__ __forceinline__ void threefry2x32(unsigned k0, unsigned k1, unsigned &x0, unsigned &x1){
  unsigned ks2 = k0 ^ k1 ^ 0x1BD11BDAu;
#define TF_R(R) { x0 += x1; x1 = (x1<<(R))|(x1>>(32-(R))); x1 ^= x0; }
  x0 += k0; x1 += k1;
  TF_R(13) TF_R(15) TF_R(26) TF_R(6)
  x0 += k1;  x1 += ks2 + 1u;
  TF_R(17) TF_R(29) TF_R(16) TF_R(24)
  x0 += ks2; x1 += k0 + 2u;
  TF_R(13) TF_R(15) TF_R(26) TF_R(6)
  x0 += k0;  x1 += k1 + 3u;
  TF_R(17) TF_R(29) TF_R(16) TF_R(24)
  x0 += k1;  x1 += ks2 + 4u;
  TF_R(13) TF_R(15) TF_R(26) TF_R(6)
  x0 += ks2; x1 += k0 + 5u;
#undef TF_R
}

__device__ __forceinline__ float dropout_val(float v, unsigned i){
  unsigned x0 = 0u, x1 = i;
  threefry2x32(0u, 42u, x0, x1);
  unsigned bits = x0 ^ x1;
  float u = __uint_as_float((bits >> 9) | 0x3f800000u) - 1.0f;
  return (u < 0.6f) ? v * (1.0f/0.6f) : 0.0f;
}

__global__ void k_probe(const int* __restrict__ ei, unsigned hostbits, float* __restrict__ out){
  if (threadIdx.x != 0 || blockIdx.x != 0) return;
  unsigned bits = hostbits;
  { unsigned a=0u, b=0u; threefry2x32(0u, 0u, a, b);
    if (a != 0x6b200159u || b != 0x99ba4efeu) bits |= 1u; }
  if (bits) out[0] = 1.0e4f * (float)bits;
}

// ---------------- utility ----------------
__global__ void k_zero_int(int* __restrict__ p, int n){
  int i = blockIdx.x*256 + threadIdx.x;
  if (i < n) p[i] = 0;
}

__global__ void k_deg(const int* __restrict__ dst, int ne, int* __restrict__ cnt){
  int i = blockIdx.x*256 + threadIdx.x;
  if (i < ne) atomicAdd(&cnt[dst[i]], 1);
}

// degree histogram + within-row rank (atomicAdd return) in ONE pass
__global__ void k_degrank(const int* __restrict__ dst, int ne, int* __restrict__ cnt,
                          int* __restrict__ rank){
  int i = blockIdx.x*256 + threadIdx.x;
  if (i >= ne) return;
  rank[i] = atomicAdd(&cnt[dst[i]], 1);
}

__global__ void k_dinv(const int* __restrict__ cnt, float* __restrict__ dinv, int n){
  int i = blockIdx.x*256 + threadIdx.x;
  if (i < n) dinv[i] = 1.0f / sqrtf((float)(cnt[i] + 1));
}

// ---------------- multi-block exclusive scan ----------------
__global__ __launch_bounds__(1024) void k_scan1(const int* __restrict__ cnt, int* __restrict__ bsum, int n){
  __shared__ int lds[1024];
  int t = threadIdx.x, i = blockIdx.x*1024 + t;
  lds[t] = (i < n) ? cnt[i] : 0;
  __syncthreads();
  for (int off = 512; off > 0; off >>= 1){
    if (t < off) lds[t] += lds[t + off];
    __syncthreads();
  }
  if (t == 0) bsum[blockIdx.x] = lds[0];
}

__global__ __launch_bounds__(128) void k_scan2(int* __restrict__ bsum, int nb){
  __shared__ int lds[128];
  int t = threadIdx.x;
  int v = (t < nb) ? bsum[t] : 0;
  lds[t] = v;
  __syncthreads();
  for (int off = 1; off < 128; off <<= 1){
    int x = (t >= off) ? lds[t - off] : 0;
    __syncthreads();
    lds[t] += x;
    __syncthreads();
  }
  if (t < nb) bsum[t] = lds[t] - v;
}

__global__ __launch_bounds__(1024) void k_scan3(const int* __restrict__ cnt, const int* __restrict__ bsum,
                                                int* __restrict__ rowptr, int n){
  __shared__ int lds[1024];
  int t = threadIdx.x, i = blockIdx.x*1024 + t;
  int v = (i < n) ? cnt[i] : 0;
  lds[t] = v;
  __syncthreads();
  for (int off = 1; off < 1024; off <<= 1){
    int x = (t >= off) ? lds[t - off] : 0;
    __syncthreads();
    lds[t] += x;
    __syncthreads();
  }
  int excl = lds[t] - v + bsum[blockIdx.x];
  if (i < n)  rowptr[i] = excl;
  if (i == n-1) rowptr[n] = excl + v;
}

// ---------------- CSR fill, atomic-free (uses precomputed rank) ----------------
__global__ void k_fillr(const int* __restrict__ src, const int* __restrict__ dst, int ne,
                        const int* __restrict__ rowptr, const int* __restrict__ rank,
                        int* __restrict__ col){
  int e = blockIdx.x*256 + threadIdx.x;
  if (e >= ne) return;
  col[rowptr[dst[e]] + rank[e]] = src[e];
}

// ---------------- legacy cursor fill (fallback path only) ----------------
__global__ void k_fill(const int* __restrict__ src, const int* __restrict__ dst, int ne,
                       const int* __restrict__ rowptr, int* __restrict__ cursor, int* __restrict__ col){
  int e = blockIdx.x*256 + threadIdx.x;
  if (e >= ne) return;
  int d = dst[e];
  int p = atomicAdd(&cursor[d], 1);
  col[rowptr[d] + p] = src[e];
}

// ---------------- GEMM [nrows,64] @ [64,64]; RELU on input; SCALE: Y[row] *= dinv[row] ----------------
template<bool RELU, bool SCALE>
__global__ __launch_bounds__(256) void k_gemm64(const float* __restrict__ X, const float* __restrict__ W,
                                                const float* __restrict__ dinv,
                                                int nrows, float* __restrict__ Y){
  __shared__ float Ws[64][64];
  int t = threadIdx.x;
  {
    const float4* W4 = (const float4*)W;
    float4* S4 = (float4*)&Ws[0][0];
    #pragma unroll
    for (int i = 0; i < 4; ++i) S4[t + 256*i] = W4[t + 256*i];
  }
  __syncthreads();
  int row = blockIdx.x*16 + (t>>4);
  if (row >= nrows) return;
  int c0 = (t & 15) * 4;
  const float4* Xr = (const float4*)(X + (size_t)row*64);
  float4 acc = make_float4(0.f,0.f,0.f,0.f);
  #pragma unroll
  for (int kk = 0; kk < 16; ++kk){
    float4 xv = Xr[kk];
    if (RELU){
      xv.x = fmaxf(xv.x, 0.f); xv.y = fmaxf(xv.y, 0.f);
      xv.z = fmaxf(xv.z, 0.f); xv.w = fmaxf(xv.w, 0.f);
    }
    int k = kk*4;
    float4 w0 = *(const float4*)&Ws[k+0][c0];
    float4 w1 = *(const float4*)&Ws[k+1][c0];
    float4 w2 = *(const float4*)&Ws[k+2][c0];
    float4 w3 = *(const float4*)&Ws[k+3][c0];
    acc.x = fmaf(xv.x, w0.x, acc.x); acc.y = fmaf(xv.x, w0.y, acc.y);
    acc.z = fmaf(xv.x, w0.z, acc.z); acc.w = fmaf(xv.x, w0.w, acc.w);
    acc.x = fmaf(xv.y, w1.x, acc.x); acc.y = fmaf(xv.y, w1.y, acc.y);
    acc.z = fmaf(xv.y, w1.z, acc.z); acc.w = fmaf(xv.y, w1.w, acc.w);
    acc.x = fmaf(xv.z, w2.x, acc.x); acc.y = fmaf(xv.z, w2.y, acc.y);
    acc.z = fmaf(xv.z, w2.z, acc.z); acc.w = fmaf(xv.z, w2.w, acc.w);
    acc.x = fmaf(xv.w, w3.x, acc.x); acc.y = fmaf(xv.w, w3.y, acc.y);
    acc.z = fmaf(xv.w, w3.z, acc.z); acc.w = fmaf(xv.w, w3.w, acc.w);
  }
  if (SCALE){
    float dv = dinv[row];
    acc.x *= dv; acc.y *= dv; acc.z *= dv; acc.w *= dv;
  }
  *(float4*)(Y + (size_t)row*64 + c0) = acc;
}

// ---------------- GEMM [nrows,64] @ [64,2] ----------------
template<bool RELU, bool SCALE>
__global__ __launch_bounds__(256) void k_gemm2(const float* __restrict__ X, const float* __restrict__ W,
                                               const float* __restrict__ dinv,
                                               int nrows, float* __restrict__ Y){
  __shared__ float Ws[128];
  int t = threadIdx.x;
  if (t < 128) Ws[t] = W[t];
  __syncthreads();
  int row = blockIdx.x*256 + t;
  if (row >= nrows) return;
  const float4* Xr = (const float4*)(X + (size_t)row*64);
  float a0 = 0.f, a1 = 0.f;
  #pragma unroll
  for (int kk = 0; kk < 16; ++kk){
    float4 xv = Xr[kk];
    if (RELU){ xv.x=fmaxf(xv.x,0.f); xv.y=fmaxf(xv.y,0.f); xv.z=fmaxf(xv.z,0.f); xv.w=fmaxf(xv.w,0.f); }
    int k = kk*4;
    a0 = fmaf(xv.x, Ws[2*k+0], a0); a1 = fmaf(xv.x, Ws[2*k+1], a1);
    a0 = fmaf(xv.y, Ws[2*k+2], a0); a1 = fmaf(xv.y, Ws[2*k+3], a1);
    a0 = fmaf(xv.z, Ws[2*k+4], a0); a1 = fmaf(xv.z, Ws[2*k+5], a1);
    a0 = fmaf(xv.w, Ws[2*k+6], a0); a1 = fmaf(xv.w, Ws[2*k+7], a1);
  }
  if (SCALE){ float dv = dinv[row]; a0 *= dv; a1 *= dv; }
  Y[(size_t)row*2]   = a0;
  Y[(size_t)row*2+1] = a1;
}

// ---------------- CSR gather conv on pre-scaled h' ----------------
__global__ __launch_bounds__(256) void k_gather64(const int* __restrict__ rowptr, const int* __restrict__ col,
                                                  const float* __restrict__ h, const float* __restrict__ dinv,
                                                  const float* __restrict__ b, float* __restrict__ out){
  int lane = threadIdx.x & 63;
  int node = (blockIdx.x*256 + threadIdx.x) >> 6;
  if (node >= NN) return;
  int beg = rowptr[node], end = rowptr[node+1];
  float acc = h[(size_t)node*64 + lane];
  int j = beg;
  for (; j + 4 <= end; j += 4){
    int s0 = col[j], s1 = col[j+1], s2 = col[j+2], s3 = col[j+3];
    float h0 = h[(size_t)s0*64 + lane];
    float h1 = h[(size_t)s1*64 + lane];
    float h2 = h[(size_t)s2*64 + lane];
    float h3 = h[(size_t)s3*64 + lane];
    acc += h0; acc += h1; acc += h2; acc += h3;
  }
  for (; j < end; ++j) acc += h[(size_t)col[j]*64 + lane];
  out[(size_t)node*64 + lane] = fmaf(acc, dinv[node], b[lane]);
}

// ---------------- CSR gather cross-layer agg (+ optional fused dropout) ----------------
template<bool DROP>
__global__ __launch_bounds__(256) void k_agggather(const int* __restrict__ rowptr, const int* __restrict__ col,
                                                    const float* __restrict__ lf, const float* __restrict__ last,
                                                    const float* __restrict__ ds, int dsidx, float* __restrict__ out){
  int lane = threadIdx.x & 63;
  int node = (blockIdx.x*256 + threadIdx.x) >> 6;
  if (node >= NN) return;
  int beg = rowptr[node], end = rowptr[node+1];
  float acc = lf[(size_t)node*64 + lane];
  int j = beg;
  for (; j + 4 <= end; j += 4){
    int s0 = col[j], s1 = col[j+1], s2 = col[j+2], s3 = col[j+3];
    float h0 = last[(size_t)s0*64 + lane];
    float h1 = last[(size_t)s1*64 + lane];
    float h2 = last[(size_t)s2*64 + lane];
    float h3 = last[(size_t)s3*64 + lane];
    acc += h0; acc += h1; acc += h2; acc += h3;
  }
  for (; j < end; ++j) acc += last[(size_t)col[j]*64 + lane];
  float val = acc / ds[dsidx];
  unsigned i = (unsigned)node*64u + (unsigned)lane;
  if (DROP) val = dropout_val(val, i);
  out[i] = val;
}

// ---------------- CSR gather final conv (D_out=2) ----------------
__global__ void k_gather2(const int* __restrict__ rowptr, const int* __restrict__ col,
                          const float* __restrict__ h2, const float* __restrict__ dinv,
                          const float* __restrict__ b, float* __restrict__ out){
  int d = blockIdx.x*256 + threadIdx.x;
  if (d >= NN) return;
  int beg = rowptr[d], end = rowptr[d+1];
  float a0 = h2[(size_t)d*2];
  float a1 = h2[(size_t)d*2+1];
  for (int j = beg; j < end; ++j){
    int s = col[j];
    a0 += h2[(size_t)s*2];
    a1 += h2[(size_t)s*2+1];
  }
  float dv = dinv[d];
  out[(size_t)d*2]   = fmaf(a0, dv, b[0]);
  out[(size_t)d*2+1] = fmaf(a1, dv, b[1]);
}

// ---------------- standalone dropout (fallback path only) ----------------
__global__ void k_dropout(const float* __restrict__ last, float* __restrict__ xemb){
  unsigned i = blockIdx.x*256 + threadIdx.x;
  if (i >= NF) return;
  xemb[i] = dropout_val(last[i], i);
}

// ======== fallback (atomic scatter) kernels ========
__global__ void k_convinit(const float* __restrict__ h, const float* __restrict__ dinv,
                           const float* __restrict__ b, float* __restrict__ out){
  int i = blockIdx.x*256 + threadIdx.x;
  if (i >= NF) return;
  int v = i >> 6, c = i & 63;
  float dv = dinv[v];
  out[i] = h[i]*dv*dv + b[c];
}
__global__ void k_scatter64(const int* __restrict__ src, const int* __restrict__ dst, int ne,
                            const float* __restrict__ h, const float* __restrict__ dinv,
                            float* __restrict__ out){
  int lane = threadIdx.x & 63;
  int wid  = (blockIdx.x*256 + threadIdx.x) >> 6;
  int nw   = (gridDim.x*256) >> 6;
  for (int e = wid; e < ne; e += nw){
    int s = src[e], d = dst[e];
    float coef = dinv[s]*dinv[d];
    atomicAdd(&out[d*64 + lane], h[s*64 + lane]*coef);
  }
}
__global__ void k_layeragg(const int* __restrict__ recv, const int* __restrict__ srcn, int ne,
                           const float* __restrict__ last, float* __restrict__ acc){
  int lane = threadIdx.x & 63;
  int wid  = (blockIdx.x*256 + threadIdx.x) >> 6;
  int nw   = (gridDim.x*256) >> 6;
  for (int e = wid; e < ne; e += nw){
    int r = recv[e], s = srcn[e];
    atomicAdd(&acc[r*64 + lane], last[s*64 + lane]);
  }
}
__global__ void k_scale(const float* __restrict__ in, const float* __restrict__ ds, int dsidx,
                        float* __restrict__ out){
  int i = blockIdx.x*256 + threadIdx.x;
  if (i < NF) out[i] = in[i] / ds[dsidx];
}
__global__ void k_convinit2(const float* __restrict__ h2, const float* __restrict__ dinv,
                            const float* __restrict__ b, float* __restrict__ out){
  int i = blockIdx.x*256 + threadIdx.x;
  if (i >= NN*2) return;
  int v = i >> 1, c = i & 1;
  float dv = dinv[v];
  out[i] = h2[i]*dv*dv + b[c];
}
__global__ void k_scatter2(const int* __restrict__ src, const int* __restrict__ dst, int ne,
                           const float* __restrict__ h2, const float* __restrict__ dinv,
                           float* __restrict__ out){
  int e = blockIdx.x*256 + threadIdx.x;
  if (e >= ne) return;
  int s = src[e], d = dst[e];
  float coef = dinv[s]*dinv[d];
  atomicAdd(&out[d*2 + 0], h2[s*2 + 0]*coef);
  atomicAdd(&out[d*2 + 1], h2[s*2 + 1]*coef);
}

extern "C" void kernel_launch(void* const* d_in, const int* in_sizes, int n_in,
                              void* d_out, int out_size, void* d_ws, size_t ws_size,
                              hipStream_t stream) {
  const float* x    = (const float*)d_in[0];
  const int*   ei   = (const int*)  d_in[1];
  const int*   lei  = (const int*)  d_in[2];
  const float* degs = (const float*)d_in[3];
  const float* lW1  = (const float*)d_in[4];
  const float* lb1  = (const float*)d_in[5];
  const float* lW2  = (const float*)d_in[6];
  const float* lb2  = (const float*)d_in[7];
  const float* pW1  = (const float*)d_in[8];
  const float* pb1  = (const float*)d_in[9];
  const float* pW2  = (const float*)d_in[10];
  const float* pb2  = (const float*)d_in[11];
  float* out = (float*)d_out;

  const int gN  = (NN + 255)/256;
  const int gE  = (EE + 255)/256;
  const int gEL = (ELL + 255)/256;
  const int gNF = (NF + 255)/256;
  const int gG  = (NN*64 + 255)/256;

  const bool dual   = ws_size >= (size_t)WS_DUAL * 4;
  const bool single = ws_size >= (size_t)WS_SINGLE * 4;

  if (single) {
    float* base   = (float*)d_ws;
    float* dinv   = base;
    int*   cnt    = (int*)(base + OFF_CNT);
    int*   bsum   = (int*)(base + OFF_BSUM);
    int*   rpA    = (int*)(base + OFF_RPA);
    int*   colA   = (int*)(base + OFF_COLA);
    int*   rpB    = dual ? (int*)(base + OFF_RPB)  : rpA;
    int*   colB   = dual ? (int*)(base + OFF_COLB) : colA;
    float* F0     = base + (dual ? OFF_COLB + 1000000 : OFF_RPB);
    float* F1     = F0 + NF;
    float* F2     = F1 + NF;

    // rank buffer aliases a provably-dead F buffer per build (consumed within the build)
    auto build_csr = [&](const int* srcp, const int* dstp, int ne, int gEdges, bool computeDinv,
                         int* rowptr, int* col, int* rank){
      k_zero_int<<<gN, 256, 0, stream>>>(cnt, NN);
      k_degrank<<<gEdges, 256, 0, stream>>>(dstp, ne, cnt, rank);
      if (computeDinv) k_dinv<<<gN, 256, 0, stream>>>(cnt, dinv, NN);
      k_scan1<<<NB_SCAN, 1024, 0, stream>>>(cnt, bsum, NN);
      k_scan2<<<1, 128, 0, stream>>>(bsum, NB_SCAN);
      k_scan3<<<NB_SCAN, 1024, 0, stream>>>(cnt, bsum, rowptr, NN);
      k_fillr<<<gEdges, 256, 0, stream>>>(srcp, dstp, ne, rowptr, rank, col);
    };

    const int* s0 = ei;                  const int* d0 = s0 + EE;
    const int* s1 = ei + 2*(size_t)EE;   const int* d1 = s1 + EE;
    const int* s2 = ei + 4*(size_t)EE;   const int* d2 = s2 + EE;
    const int* r0 = lei;                 const int* ls0 = r0 + ELL;
    const int* r1 = lei + 2*(size_t)ELL; const int* ls1 = r1 + ELL;

    // ---- surface 0 ----  (F0 dead during build)
    build_csr(s0, d0, EE, gE, true, rpA, colA, (int*)F0);
    k_gemm64<false,true><<<6250, 256, 0, stream>>>(x, lW1, dinv, NN, F0);
    k_gather64<<<gG, 256, 0, stream>>>(rpA, colA, F0, dinv, lb1, F1);
    k_gemm64<true,true><<<6250, 256, 0, stream>>>(F1, lW2, dinv, NN, F0);
    k_gather64<<<gG, 256, 0, stream>>>(rpA, colA, F0, dinv, lb2, F2);            // last = F2
    // ---- surface 1 ----  (F0 dead during both builds)
    build_csr(s1, d1, EE, gE, true, rpA, colA, (int*)F0);
    k_gemm64<false,true><<<6250, 256, 0, stream>>>(x + (size_t)NF, lW1 + 4096, dinv, NN, F0);
    k_gather64<<<gG, 256, 0, stream>>>(rpA, colA, F0, dinv, lb1 + 64, F1);
    k_gemm64<true,true><<<6250, 256, 0, stream>>>(F1, lW2 + 4096, dinv, NN, F0);
    k_gather64<<<gG, 256, 0, stream>>>(rpA, colA, F0, dinv, lb2 + 64, F1);       // lf = F1
    build_csr(ls0, r0, ELL, gEL, false, rpB, colB, (int*)F0);
    k_agggather<false><<<gG, 256, 0, stream>>>(rpB, colB, F1, F2, degs, 0, F0);  // last = F0
    // ---- surface 2 ----  (F1 dead during both builds)
    build_csr(s2, d2, EE, gE, true, rpA, colA, (int*)F1);
    k_gemm64<false,true><<<6250, 256, 0, stream>>>(x + 2*(size_t)NF, lW1 + 8192, dinv, NN, F1);
    k_gather64<<<gG, 256, 0, stream>>>(rpA, colA, F1, dinv, lb1 + 128, F2);
    k_gemm64<true,true><<<6250, 256, 0, stream>>>(F2, lW2 + 8192, dinv, NN, F1);
    k_gather64<<<gG, 256, 0, stream>>>(rpA, colA, F1, dinv, lb2 + 128, F2);      // lf = F2
    build_csr(ls1, r1, ELL, gEL, false, rpB, colB, (int*)F1);
    k_agggather<true><<<gG, 256, 0, stream>>>(rpB, colB, F2, F0, degs, 1, F1);   // F1 = x_emb (dropout fused)
    // ---- predictor (edge set 2) ----  (F0 dead during build)
    if (!dual) build_csr(s2, d2, EE, gE, false, rpA, colA, (int*)F0);
    k_gemm64<false,true><<<6250, 256, 0, stream>>>(F1, pW1, dinv, NN, F0);
    k_gather64<<<gG, 256, 0, stream>>>(rpA, colA, F0, dinv, pb1, F2);
    k_gemm2<true,true><<<gN, 256, 0, stream>>>(F2, pW2, dinv, NN, F1);
    k_gather2<<<gN, 256, 0, stream>>>(rpA, colA, F1, dinv, pb2, out);
    k_probe<<<1, 64, 0, stream>>>(ei, 0u, out);
    return;
  }

  // ================= fallback: verified atomic-scatter path =================
  float* base = (float*)d_ws;
  float* dinv = base;
  int*   cnt  = (int*)(base + 100352);
  float* A    = base + 262144;
  float* B    = A + NF;
  float* C    = B + NF;

  for (int i = 0; i < 3; ++i){
    const int* srcp = ei + (size_t)i*2*EE;
    const int* dstp = srcp + EE;
    k_zero_int<<<gN, 256, 0, stream>>>(cnt, NN);
    k_deg<<<gE, 256, 0, stream>>>(dstp, EE, cnt);
    k_dinv<<<gN, 256, 0, stream>>>(cnt, dinv, NN);
    k_gemm64<false,false><<<6250, 256, 0, stream>>>(x + (size_t)i*NF, lW1 + (size_t)i*64*64, dinv, NN, A);
    k_convinit<<<gNF, 256, 0, stream>>>(A, dinv, lb1 + (size_t)i*64, B);
    k_scatter64<<<8192, 256, 0, stream>>>(srcp, dstp, EE, A, dinv, B);
    k_gemm64<true,false><<<6250, 256, 0, stream>>>(B, lW2 + (size_t)i*64*64, dinv, NN, A);
    float* T = (i == 0) ? C : B;
    k_convinit<<<gNF, 256, 0, stream>>>(A, dinv, lb2 + (size_t)i*64, T);
    k_scatter64<<<8192, 256, 0, stream>>>(srcp, dstp, EE, A, dinv, T);
    if (i > 0){
      const int* recvp = lei + (size_t)(i-1)*2*ELL;
      const int* lsrcp = recvp + ELL;
      k_layeragg<<<4096, 256, 0, stream>>>(recvp, lsrcp, ELL, C, B);
      k_scale<<<gNF, 256, 0, stream>>>(B, degs, i-1, C);
    }
  }
  k_dropout<<<gNF, 256, 0, stream>>>(C, B);
  const int* srcp = ei + (size_t)2*2*EE;
  const int* dstp = srcp + EE;
  k_gemm64<false,false><<<6250, 256, 0, stream>>>(B, pW1, dinv, NN, A);
  k_convinit<<<gNF, 256, 0, stream>>>(A, dinv, pb1, C);
  k_scatter64<<<8192, 256, 0, stream>>>(srcp, dstp, EE, A, dinv, C);
  k_gemm2<true,false><<<gN, 256, 0, stream>>>(C, pW2, dinv, NN, B);
  k_convinit2<<<(NN*2 + 255)/256, 256, 0, stream>>>(B, dinv, pb2, out);
  k_scatter2<<<gE, 256, 0, stream>>>(srcp, dstp, EE, B, dinv, out);
  k_probe<<<1, 64, 0, stream>>>(ei, 0u, out);
}